// Round 1
// baseline (6796.965 us; speedup 1.0000x reference)
//
#include <hip/hip_runtime.h>
#include <math.h>

#define B_ 256
#define E_ 128
#define N_ 128
#define T_ 20
#define D_ 128
#define M_ (B_*E_)   // 32768 sequences

__device__ __forceinline__ float sigm(float x) { return 1.0f / (1.0f + __expf(-x)); }
__device__ __forceinline__ float dot4(float4 a, float4 b) {
    return a.x*b.x + a.y*b.y + a.z*b.z + a.w*b.w;
}

// ---------------------------------------------------------------------------
// K1: micro-GRU. 16 sequences per block, 256 threads.
// Thread layout: d = tid&127 (output column), sg = tid>>7; each thread owns
// sequences s = sg + 2p (p=0..7). All 6 gate dot-products for an (s,d) pair
// are computed by one thread, so no cross-thread gate exchange is needed.
// h and x_t live in LDS (broadcast reads, conflict-free).
// ---------------------------------------------------------------------------
__global__ __launch_bounds__(256) void k1_gru(
    const float* __restrict__ xa,   // [M, T, D]
    const int*   __restrict__ len,  // [M]
    const float* __restrict__ wih,  // [3D, D]
    const float* __restrict__ whh,  // [3D, D]
    const float* __restrict__ bih,  // [3D]
    const float* __restrict__ bhh,  // [3D]
    float* __restrict__ mh)         // [M, D] (aliased onto d_out)
{
    __shared__ float xs[16][128];
    __shared__ float hs[16][128];
    const int tid = threadIdx.x;
    const int d   = tid & 127;
    const int sg  = tid >> 7;
    const int m0  = blockIdx.x * 16;

    for (int i = tid; i < 16*128; i += 256) (&hs[0][0])[i] = 0.0f;

    int mylen[8];
#pragma unroll
    for (int p = 0; p < 8; ++p) mylen[p] = len[m0 + sg + 2*p];

    const float brz = bih[d]       + bhh[d];        // r gate: biases combine
    const float bzz = bih[d + 128] + bhh[d + 128];  // z gate
    const float bin = bih[d + 256];                  // i_n (separate: r*h_n)
    const float bhn = bhh[d + 256];                  // h_n

    const float4* wr4 = (const float4*)(wih + (size_t)(d        ) * D_);
    const float4* wz4 = (const float4*)(wih + (size_t)(d + 128  ) * D_);
    const float4* wn4 = (const float4*)(wih + (size_t)(d + 256  ) * D_);
    const float4* ur4 = (const float4*)(whh + (size_t)(d        ) * D_);
    const float4* uz4 = (const float4*)(whh + (size_t)(d + 128  ) * D_);
    const float4* un4 = (const float4*)(whh + (size_t)(d + 256  ) * D_);

    __syncthreads();

    for (int t = 0; t < T_; ++t) {
        // stage x_t for the block's 16 sequences (coalesced)
        for (int i = tid; i < 16*128; i += 256) {
            int s = i >> 7, dd = i & 127;
            xs[s][dd] = xa[(size_t)(m0 + s) * (T_ * D_) + (size_t)t * D_ + dd];
        }
        __syncthreads();

        float ar[8], az[8], ain[8], ahn[8];
#pragma unroll
        for (int p = 0; p < 8; ++p) { ar[p] = brz; az[p] = bzz; ain[p] = bin; ahn[p] = bhn; }

        for (int k4 = 0; k4 < 32; ++k4) {
            float4 wr = wr4[k4], wz = wz4[k4], wn = wn4[k4];
            float4 ur = ur4[k4], uz = uz4[k4], un = un4[k4];
#pragma unroll
            for (int p = 0; p < 8; ++p) {
                int s = sg + 2*p;
                float4 x4 = *(const float4*)&xs[s][k4 * 4];
                float4 h4 = *(const float4*)&hs[s][k4 * 4];
                ar[p]  += dot4(wr, x4) + dot4(ur, h4);
                az[p]  += dot4(wz, x4) + dot4(uz, h4);
                ain[p] += dot4(wn, x4);
                ahn[p] += dot4(un, h4);
            }
        }
        __syncthreads();   // all reads of hs complete before updates

#pragma unroll
        for (int p = 0; p < 8; ++p) {
            if (t < mylen[p]) {
                int s = sg + 2*p;
                float r = sigm(ar[p]);
                float z = sigm(az[p]);
                float n = tanhf(ain[p] + r * ahn[p]);
                hs[s][d] = (1.0f - z) * n + z * hs[s][d];  // PyTorch GRU update
            }
        }
        __syncthreads();
    }

#pragma unroll
    for (int p = 0; p < 8; ++p) {
        int s = sg + 2*p;
        mh[(size_t)(m0 + s) * D_ + d] = hs[s][d];
    }
}

// ---------------------------------------------------------------------------
// K2: h_in/h_out = [macro_items | mh] @ {w_in,w_out}^T + bias.
// 16 rows per block; concat row staged in LDS.
// ---------------------------------------------------------------------------
__global__ __launch_bounds__(256) void k2_edges(
    const float* __restrict__ mi,    // [M, D] macro_items
    const float* __restrict__ mh,    // [M, D] (in d_out)
    const float* __restrict__ w_in,  // [D, 2D]
    const float* __restrict__ b_in,  // [D]
    const float* __restrict__ w_out, // [D, 2D]
    const float* __restrict__ b_out, // [D]
    float* __restrict__ hin,         // [M, D] (ws)
    float* __restrict__ hout)        // [M, D] (ws)
{
    __shared__ float cat[16][256];
    const int tid = threadIdx.x;
    const int d  = tid & 127;
    const int sg = tid >> 7;
    const int r0 = blockIdx.x * 16;

    for (int i = tid; i < 16*256; i += 256) {
        int r = i >> 8, c = i & 255;
        cat[r][c] = (c < 128) ? mi[(size_t)(r0 + r) * D_ + c]
                              : mh[(size_t)(r0 + r) * D_ + (c - 128)];
    }
    __syncthreads();

    const float4* wi4 = (const float4*)(w_in  + (size_t)d * 256);
    const float4* wo4 = (const float4*)(w_out + (size_t)d * 256);

    float hi[8], ho[8];
#pragma unroll
    for (int p = 0; p < 8; ++p) { hi[p] = b_in[d]; ho[p] = b_out[d]; }

    for (int k4 = 0; k4 < 64; ++k4) {
        float4 wi = wi4[k4], wo = wo4[k4];
#pragma unroll
        for (int p = 0; p < 8; ++p) {
            int r = sg + 2*p;
            float4 c4 = *(const float4*)&cat[r][k4 * 4];
            hi[p] += dot4(wi, c4);
            ho[p] += dot4(wo, c4);
        }
    }
#pragma unroll
    for (int p = 0; p < 8; ++p) {
        int r = sg + 2*p;
        hin [(size_t)(r0 + r) * D_ + d] = hi[p];
        hout[(size_t)(r0 + r) * D_ + d] = ho[p];
    }
}

// ---------------------------------------------------------------------------
// K3: fused einsum('bne,bed->bnd') + GNN gate. One block per (b, 32-row
// n-tile). A-tile staged in LDS; same LDS buffer is reused to hold the
// 'inputs' rows after phase 1 (stays at 32 KB -> 5 blocks/CU).
// ---------------------------------------------------------------------------
__global__ __launch_bounds__(256) void k3_gate(
    const float* __restrict__ A,      // [B, N, 2E]
    const float* __restrict__ hidden, // [B, N, D]
    const float* __restrict__ hin,    // [B, E, D]
    const float* __restrict__ hout,   // [B, E, D]
    const float* __restrict__ wih,    // [3D, 2D]
    const float* __restrict__ whh,    // [3D, D]
    const float* __restrict__ bih,    // [3D]
    const float* __restrict__ bhh,    // [3D]
    const float* __restrict__ biah,   // [D]
    const float* __restrict__ bioh,   // [D]
    float* __restrict__ out)          // [B, N, D]
{
    __shared__ float As[32][256];     // A tile; becomes 'inputs' after phase 1
    const int tid = threadIdx.x;
    const int d   = tid & 127;
    const int sg  = tid >> 7;
    const int b   = blockIdx.x >> 2;
    const int n0  = (blockIdx.x & 3) * 32;

    for (int i = tid; i < 32*256; i += 256) {
        int n = i >> 8, c = i & 255;
        As[n][c] = A[(size_t)b * N_ * 256 + (size_t)(n0 + n) * 256 + c];
    }
    __syncthreads();

    // ---- phase 1: input_in / input_out -----------------------------------
    float ain[16], aout[16];
#pragma unroll
    for (int p = 0; p < 16; ++p) { ain[p] = 0.0f; aout[p] = 0.0f; }

    const float* hinb  = hin  + (size_t)b * E_ * D_;
    const float* houtb = hout + (size_t)b * E_ * D_;

    for (int e0 = 0; e0 < 128; e0 += 4) {
        float hi0 = hinb [(size_t)(e0 + 0) * D_ + d];
        float hi1 = hinb [(size_t)(e0 + 1) * D_ + d];
        float hi2 = hinb [(size_t)(e0 + 2) * D_ + d];
        float hi3 = hinb [(size_t)(e0 + 3) * D_ + d];
        float ho0 = houtb[(size_t)(e0 + 0) * D_ + d];
        float ho1 = houtb[(size_t)(e0 + 1) * D_ + d];
        float ho2 = houtb[(size_t)(e0 + 2) * D_ + d];
        float ho3 = houtb[(size_t)(e0 + 3) * D_ + d];
#pragma unroll
        for (int p = 0; p < 16; ++p) {
            int nl = sg + 2*p;
            float4 a4 = *(const float4*)&As[nl][e0];        // A[:, :E] part
            float4 o4 = *(const float4*)&As[nl][128 + e0];  // A[:, E:] part
            ain[p]  += a4.x*hi0 + a4.y*hi1 + a4.z*hi2 + a4.w*hi3;
            aout[p] += o4.x*ho0 + o4.y*ho1 + o4.z*ho2 + o4.w*ho3;
        }
    }
    __syncthreads();   // everyone done reading A tile

    // overwrite As with inputs = [input_in | input_out]
#pragma unroll
    for (int p = 0; p < 16; ++p) {
        int nl = sg + 2*p;
        As[nl][d]       = ain[p]  + biah[d];
        As[nl][128 + d] = aout[p] + bioh[d];
    }
    __syncthreads();

    // ---- phase 2: gates ---------------------------------------------------
    float cr[16], cz[16], cn[16], chn[16];
    const float brz = bih[d]       + bhh[d];
    const float bzz = bih[d + 128] + bhh[d + 128];
    const float bnn = bih[d + 256];
    const float bhn = bhh[d + 256];
#pragma unroll
    for (int p = 0; p < 16; ++p) { cr[p] = brz; cz[p] = bzz; cn[p] = bnn; chn[p] = bhn; }

    const float4* wir4 = (const float4*)(wih + (size_t)(d      ) * 256);
    const float4* wiz4 = (const float4*)(wih + (size_t)(d + 128) * 256);
    const float4* win4 = (const float4*)(wih + (size_t)(d + 256) * 256);

    for (int k4 = 0; k4 < 64; ++k4) {
        float4 wr = wir4[k4], wz = wiz4[k4], wn = win4[k4];
#pragma unroll
        for (int p = 0; p < 16; ++p) {
            int nl = sg + 2*p;
            float4 i4 = *(const float4*)&As[nl][k4 * 4];
            cr[p] += dot4(wr, i4);
            cz[p] += dot4(wz, i4);
            cn[p] += dot4(wn, i4);
        }
    }

    const float4* ur4 = (const float4*)(whh + (size_t)(d      ) * D_);
    const float4* uz4 = (const float4*)(whh + (size_t)(d + 128) * D_);
    const float4* un4 = (const float4*)(whh + (size_t)(d + 256) * D_);
    const float* hidb = hidden + (size_t)b * N_ * D_ + (size_t)n0 * D_;

    for (int k4 = 0; k4 < 32; ++k4) {
        float4 ur = ur4[k4], uz = uz4[k4], un = un4[k4];
#pragma unroll
        for (int p = 0; p < 16; ++p) {
            int nl = sg + 2*p;
            float4 h4 = *(const float4*)&hidb[(size_t)nl * D_ + k4 * 4]; // broadcast, L1-hot
            cr[p]  += dot4(ur, h4);
            cz[p]  += dot4(uz, h4);
            chn[p] += dot4(un, h4);
        }
    }

#pragma unroll
    for (int p = 0; p < 16; ++p) {
        int nl = sg + 2*p;
        float hv = hidb[(size_t)nl * D_ + d];
        float r  = sigm(cr[p]);
        float z  = sigm(cz[p]);
        float ng = tanhf(cn[p] + r * chn[p]);
        out[(size_t)b * N_ * D_ + (size_t)(n0 + nl) * D_ + d] = (1.0f - z) * hv + z * ng;
    }
}

// ---------------------------------------------------------------------------
extern "C" void kernel_launch(void* const* d_in, const int* in_sizes, int n_in,
                              void* d_out, int out_size, void* d_ws, size_t ws_size,
                              hipStream_t stream) {
    const float* A     = (const float*)d_in[0];
    const float* hidden= (const float*)d_in[1];
    const float* mi    = (const float*)d_in[2];
    const float* xa    = (const float*)d_in[3];
    const int*   len   = (const int*)  d_in[4];
    const float* gwih  = (const float*)d_in[5];
    const float* gwhh  = (const float*)d_in[6];
    const float* gbih  = (const float*)d_in[7];
    const float* gbhh  = (const float*)d_in[8];
    const float* wih   = (const float*)d_in[9];
    const float* whh   = (const float*)d_in[10];
    const float* bih   = (const float*)d_in[11];
    const float* bhh   = (const float*)d_in[12];
    const float* biah  = (const float*)d_in[13];
    const float* bioh  = (const float*)d_in[14];
    const float* w_in  = (const float*)d_in[15];
    const float* b_in  = (const float*)d_in[16];
    const float* w_out = (const float*)d_in[17];
    const float* b_out = (const float*)d_in[18];

    float* out = (float*)d_out;
    // mh [M,D] has exactly the same element count as d_out [B,N,D] (N==E):
    // use d_out as the mh scratch; K3 overwrites it last.
    float* mh   = out;
    float* hin  = (float*)d_ws;                    // [M, D]
    float* hout = hin + (size_t)M_ * D_;           // [M, D]  (needs 33.6 MB ws)

    k1_gru  <<<M_ / 16, 256, 0, stream>>>(xa, len, gwih, gwhh, gbih, gbhh, mh);
    k2_edges<<<M_ / 16, 256, 0, stream>>>(mi, mh, w_in, b_in, w_out, b_out, hin, hout);
    k3_gate <<<B_ * 4,  256, 0, stream>>>(A, hidden, hin, hout, wih, whh, bih, bhh,
                                          biah, bioh, out);
}

// Round 2
// 878.788 us; speedup vs baseline: 7.7345x; 7.7345x over previous
//
#include <hip/hip_runtime.h>
#include <math.h>

#define B_ 256
#define E_ 128
#define N_ 128
#define T_ 20
#define D_ 128
#define M_ (B_*E_)   // 32768 sequences

typedef __attribute__((ext_vector_type(8))) short bf16x8;
typedef __attribute__((ext_vector_type(4))) float f32x4;

__device__ __forceinline__ float sigm(float x) { return 1.0f / (1.0f + __expf(-x)); }
__device__ __forceinline__ float fast_tanh(float x) {
    float e = __expf(2.f * x);
    return 1.f - 2.f / (e + 1.f);
}
__device__ __forceinline__ short f2bf(float f) {   // RNE float->bf16
    unsigned u = __builtin_bit_cast(unsigned, f);
    u += 0x7fffu + ((u >> 16) & 1u);
    return (short)(u >> 16);
}
__device__ __forceinline__ float dot4(float4 a, float4 b) {
    return a.x*b.x + a.y*b.y + a.z*b.z + a.w*b.w;
}

// ---------------------------------------------------------------------------
// K1: persistent MFMA micro-GRU. 32 sequences/block, 256 threads (4 waves),
// loops all T=20 steps. h master state in fp32 registers; per-step input tile
// IN = [X_t | H] as bf16 in LDS ([32 rows][256 cols], XOR-swizzled).
// Weights as bf16 B-fragments pinned in VGPRs (converted once).
// Gate-tile assignment: wave w owns d-tiles {2w, 2w+1}; its 6 g-tiles are
// {r: 2w,2w+1, z: 8+2w,8+2w+1, n: 16+2w,16+2w+1} so the r/z/n values for one
// (m, d) land in the same lane/reg -> lane-local epilogue.
// ---------------------------------------------------------------------------
__global__ __launch_bounds__(256, 1) void k1_gru_mfma(
    const float* __restrict__ xa,   // [M, T, D]
    const int*   __restrict__ len,  // [M]
    const float* __restrict__ wih,  // [3D, D]
    const float* __restrict__ whh,  // [3D, D]
    const float* __restrict__ bih,  // [3D]
    const float* __restrict__ bhh,  // [3D]
    float* __restrict__ mh)         // [M, D]
{
    __shared__ __align__(16) char inT[32 * 512];  // [32][256] bf16, swizzled

    const int tid = threadIdx.x;
    const int l   = tid & 63;
    const int w   = tid >> 6;     // wave id 0..3
    const int l15 = l & 15;
    const int l4  = l >> 4;
    const int m0  = blockIdx.x * 32;

    // ---- persistent weight fragments: wf[s][jj][kt], s=0:w_ih s=1:w_hh ----
    // B-frag for mfma_16x16x32: lane holds B[k][g]=W[g][k] at g=g0+(l&15),
    // k = kt*32 + (l>>4)*8 + j  -> 8 contiguous floats of W row g.
    bf16x8 wf[2][6][4];
    {
        const int kg = l4 * 8;
#pragma unroll
        for (int s = 0; s < 2; ++s) {
            const float* W = s ? whh : wih;
#pragma unroll
            for (int jj = 0; jj < 6; ++jj) {
                int grow = (jj >> 1) * 128 + (w * 2 + (jj & 1)) * 16 + l15;
#pragma unroll
                for (int kt = 0; kt < 4; ++kt) {
                    const float* p = W + (size_t)grow * 128 + kt * 32 + kg;
                    float4 u = *(const float4*)p;
                    float4 v = *(const float4*)(p + 4);
                    bf16x8 f;
                    f[0]=f2bf(u.x); f[1]=f2bf(u.y); f[2]=f2bf(u.z); f[3]=f2bf(u.w);
                    f[4]=f2bf(v.x); f[5]=f2bf(v.y); f[6]=f2bf(v.z); f[7]=f2bf(v.w);
                    wf[s][jj][kt] = f;
                }
            }
        }
    }

    // ---- biases / lens (lane-local) ----
    float brz[2], bzz[2], bin_[2], bhn_[2];
#pragma unroll
    for (int p = 0; p < 2; ++p) {
        int d = (w * 2 + p) * 16 + l15;
        brz[p] = bih[d]       + bhh[d];
        bzz[p] = bih[128 + d] + bhh[128 + d];
        bin_[p]= bih[256 + d];
        bhn_[p]= bhh[256 + d];
    }
    int lenv[8];
#pragma unroll
    for (int mt = 0; mt < 2; ++mt)
#pragma unroll
        for (int r = 0; r < 4; ++r)
            lenv[mt * 4 + r] = len[m0 + mt * 16 + l4 * 4 + r];

    float hm[2][2][4];
#pragma unroll
    for (int mt = 0; mt < 2; ++mt)
#pragma unroll
        for (int p = 0; p < 2; ++p)
#pragma unroll
            for (int r = 0; r < 4; ++r) hm[mt][p][r] = 0.f;

    // ---- X staging: thread -> (row sr, 16 cols at sc) ----
    const int sr = tid >> 3;          // 0..31
    const int sc = (tid & 7) * 16;    // col in elems
    const float* xbase = xa + (size_t)(m0 + sr) * (T_ * D_) + sc;
    float4 xp0, xp1, xp2, xp3;
    { const float4* p = (const float4*)xbase; xp0=p[0]; xp1=p[1]; xp2=p[2]; xp3=p[3]; }

#pragma unroll 1
    for (int t = 0; t < T_; ++t) {
        // stage X_t from prefetch regs -> LDS bf16 (swizzled)
        {
            bf16x8 c0, c1;
            c0[0]=f2bf(xp0.x); c0[1]=f2bf(xp0.y); c0[2]=f2bf(xp0.z); c0[3]=f2bf(xp0.w);
            c0[4]=f2bf(xp1.x); c0[5]=f2bf(xp1.y); c0[6]=f2bf(xp1.z); c0[7]=f2bf(xp1.w);
            c1[0]=f2bf(xp2.x); c1[1]=f2bf(xp2.y); c1[2]=f2bf(xp2.z); c1[3]=f2bf(xp2.w);
            c1[4]=f2bf(xp3.x); c1[5]=f2bf(xp3.y); c1[6]=f2bf(xp3.z); c1[7]=f2bf(xp3.w);
            int cb0 = sc * 2;
            int sw  = (sr & 7) << 4;
            *(bf16x8*)(inT + sr * 512 + ((cb0     ) ^ sw)) = c0;
            *(bf16x8*)(inT + sr * 512 + ((cb0 + 16) ^ sw)) = c1;
        }
        __syncthreads();   // barrier1: X_t (and h_t from prev iter) visible

        if (t + 1 < T_) {  // prefetch X_{t+1} (hides HBM latency under MFMA)
            const float4* p = (const float4*)(xbase + (t + 1) * D_);
            xp0 = p[0]; xp1 = p[1]; xp2 = p[2]; xp3 = p[3];
        }

        f32x4 ax[2][6], ah[2][6];
#pragma unroll
        for (int mt = 0; mt < 2; ++mt)
#pragma unroll
            for (int jj = 0; jj < 6; ++jj) {
                ax[mt][jj] = (f32x4){0.f,0.f,0.f,0.f};
                ah[mt][jj] = (f32x4){0.f,0.f,0.f,0.f};
            }

        // X phase: gi = X_t @ w_ih^T
#pragma unroll
        for (int kt = 0; kt < 4; ++kt) {
            int cb = kt * 64 + l4 * 16;
            int r0 = l15, r1 = 16 + l15;
            bf16x8 a0 = *(const bf16x8*)(inT + r0 * 512 + (cb ^ ((r0 & 7) << 4)));
            bf16x8 a1 = *(const bf16x8*)(inT + r1 * 512 + (cb ^ ((r1 & 7) << 4)));
#pragma unroll
            for (int jj = 0; jj < 6; ++jj) {
                ax[0][jj] = __builtin_amdgcn_mfma_f32_16x16x32_bf16(a0, wf[0][jj][kt], ax[0][jj], 0, 0, 0);
                ax[1][jj] = __builtin_amdgcn_mfma_f32_16x16x32_bf16(a1, wf[0][jj][kt], ax[1][jj], 0, 0, 0);
            }
        }
        // H phase: gh = H @ w_hh^T (skip at t=0: H=0 -> gh contribution 0)
        if (t > 0) {
#pragma unroll
            for (int kt = 0; kt < 4; ++kt) {
                int cb = 256 + kt * 64 + l4 * 16;
                int r0 = l15, r1 = 16 + l15;
                bf16x8 a0 = *(const bf16x8*)(inT + r0 * 512 + (cb ^ ((r0 & 7) << 4)));
                bf16x8 a1 = *(const bf16x8*)(inT + r1 * 512 + (cb ^ ((r1 & 7) << 4)));
#pragma unroll
                for (int jj = 0; jj < 6; ++jj) {
                    ah[0][jj] = __builtin_amdgcn_mfma_f32_16x16x32_bf16(a0, wf[1][jj][kt], ah[0][jj], 0, 0, 0);
                    ah[1][jj] = __builtin_amdgcn_mfma_f32_16x16x32_bf16(a1, wf[1][jj][kt], ah[1][jj], 0, 0, 0);
                }
            }
        }

        // epilogue (registers only): gates + h update
        float hb[2][2][4];
#pragma unroll
        for (int mt = 0; mt < 2; ++mt)
#pragma unroll
            for (int p = 0; p < 2; ++p)
#pragma unroll
                for (int r = 0; r < 4; ++r) {
                    float gr = ax[mt][0 + p][r] + ah[mt][0 + p][r] + brz[p];
                    float gz = ax[mt][2 + p][r] + ah[mt][2 + p][r] + bzz[p];
                    float gi = ax[mt][4 + p][r] + bin_[p];
                    float gh = ah[mt][4 + p][r] + bhn_[p];
                    float rr = sigm(gr), zz = sigm(gz);
                    float nn = fast_tanh(gi + rr * gh);
                    float hold = hm[mt][p][r];
                    float hnew = (1.f - zz) * nn + zz * hold;
                    hnew = (t < lenv[mt * 4 + r]) ? hnew : hold;
                    hm[mt][p][r] = hnew;
                    hb[mt][p][r] = hnew;
                }

        __syncthreads();   // barrier2: all waves done READING h_t region

        // write h_{t+1} (bf16) into H region for next step's A-frags
#pragma unroll
        for (int mt = 0; mt < 2; ++mt)
#pragma unroll
            for (int p = 0; p < 2; ++p)
#pragma unroll
                for (int r = 0; r < 4; ++r) {
                    int row = mt * 16 + l4 * 4 + r;
                    int cb  = 256 + (w * 2 + p) * 32 + l15 * 2;
                    *(short*)(inT + row * 512 + (cb ^ ((row & 7) << 4))) = f2bf(hb[mt][p][r]);
                }
    }

    // final h -> mh (fp32)
#pragma unroll
    for (int mt = 0; mt < 2; ++mt)
#pragma unroll
        for (int p = 0; p < 2; ++p)
#pragma unroll
            for (int r = 0; r < 4; ++r) {
                int m = m0 + mt * 16 + l4 * 4 + r;
                int d = (w * 2 + p) * 16 + l15;
                mh[(size_t)m * D_ + d] = hm[mt][p][r];
            }
}

// ---------------------------------------------------------------------------
// K2: h_in/h_out = [macro_items | mh] @ {w_in,w_out}^T + bias. (unchanged)
// ---------------------------------------------------------------------------
__global__ __launch_bounds__(256) void k2_edges(
    const float* __restrict__ mi, const float* __restrict__ mh,
    const float* __restrict__ w_in, const float* __restrict__ b_in,
    const float* __restrict__ w_out, const float* __restrict__ b_out,
    float* __restrict__ hin, float* __restrict__ hout)
{
    __shared__ float cat[16][256];
    const int tid = threadIdx.x;
    const int d  = tid & 127;
    const int sg = tid >> 7;
    const int r0 = blockIdx.x * 16;

    for (int i = tid; i < 16*256; i += 256) {
        int r = i >> 8, c = i & 255;
        cat[r][c] = (c < 128) ? mi[(size_t)(r0 + r) * D_ + c]
                              : mh[(size_t)(r0 + r) * D_ + (c - 128)];
    }
    __syncthreads();

    const float4* wi4 = (const float4*)(w_in  + (size_t)d * 256);
    const float4* wo4 = (const float4*)(w_out + (size_t)d * 256);

    float hi[8], ho[8];
#pragma unroll
    for (int p = 0; p < 8; ++p) { hi[p] = b_in[d]; ho[p] = b_out[d]; }

    for (int k4 = 0; k4 < 64; ++k4) {
        float4 wi = wi4[k4], wo = wo4[k4];
#pragma unroll
        for (int p = 0; p < 8; ++p) {
            int r = sg + 2*p;
            float4 c4 = *(const float4*)&cat[r][k4 * 4];
            hi[p] += dot4(wi, c4);
            ho[p] += dot4(wo, c4);
        }
    }
#pragma unroll
    for (int p = 0; p < 8; ++p) {
        int r = sg + 2*p;
        hin [(size_t)(r0 + r) * D_ + d] = hi[p];
        hout[(size_t)(r0 + r) * D_ + d] = ho[p];
    }
}

// ---------------------------------------------------------------------------
// K3: fused einsum + GNN gate. (unchanged)
// ---------------------------------------------------------------------------
__global__ __launch_bounds__(256) void k3_gate(
    const float* __restrict__ A, const float* __restrict__ hidden,
    const float* __restrict__ hin, const float* __restrict__ hout,
    const float* __restrict__ wih, const float* __restrict__ whh,
    const float* __restrict__ bih, const float* __restrict__ bhh,
    const float* __restrict__ biah, const float* __restrict__ bioh,
    float* __restrict__ out)
{
    __shared__ float As[32][256];
    const int tid = threadIdx.x;
    const int d   = tid & 127;
    const int sg  = tid >> 7;
    const int b   = blockIdx.x >> 2;
    const int n0  = (blockIdx.x & 3) * 32;

    for (int i = tid; i < 32*256; i += 256) {
        int n = i >> 8, c = i & 255;
        As[n][c] = A[(size_t)b * N_ * 256 + (size_t)(n0 + n) * 256 + c];
    }
    __syncthreads();

    float ain[16], aout[16];
#pragma unroll
    for (int p = 0; p < 16; ++p) { ain[p] = 0.0f; aout[p] = 0.0f; }

    const float* hinb  = hin  + (size_t)b * E_ * D_;
    const float* houtb = hout + (size_t)b * E_ * D_;

    for (int e0 = 0; e0 < 128; e0 += 4) {
        float hi0 = hinb [(size_t)(e0 + 0) * D_ + d];
        float hi1 = hinb [(size_t)(e0 + 1) * D_ + d];
        float hi2 = hinb [(size_t)(e0 + 2) * D_ + d];
        float hi3 = hinb [(size_t)(e0 + 3) * D_ + d];
        float ho0 = houtb[(size_t)(e0 + 0) * D_ + d];
        float ho1 = houtb[(size_t)(e0 + 1) * D_ + d];
        float ho2 = houtb[(size_t)(e0 + 2) * D_ + d];
        float ho3 = houtb[(size_t)(e0 + 3) * D_ + d];
#pragma unroll
        for (int p = 0; p < 16; ++p) {
            int nl = sg + 2*p;
            float4 a4 = *(const float4*)&As[nl][e0];
            float4 o4 = *(const float4*)&As[nl][128 + e0];
            ain[p]  += a4.x*hi0 + a4.y*hi1 + a4.z*hi2 + a4.w*hi3;
            aout[p] += o4.x*ho0 + o4.y*ho1 + o4.z*ho2 + o4.w*ho3;
        }
    }
    __syncthreads();

#pragma unroll
    for (int p = 0; p < 16; ++p) {
        int nl = sg + 2*p;
        As[nl][d]       = ain[p]  + biah[d];
        As[nl][128 + d] = aout[p] + bioh[d];
    }
    __syncthreads();

    float cr[16], cz[16], cn[16], chn[16];
    const float brz = bih[d]       + bhh[d];
    const float bzz = bih[d + 128] + bhh[d + 128];
    const float bnn = bih[d + 256];
    const float bhn = bhh[d + 256];
#pragma unroll
    for (int p = 0; p < 16; ++p) { cr[p] = brz; cz[p] = bzz; cn[p] = bnn; chn[p] = bhn; }

    const float4* wir4 = (const float4*)(wih + (size_t)(d      ) * 256);
    const float4* wiz4 = (const float4*)(wih + (size_t)(d + 128) * 256);
    const float4* win4 = (const float4*)(wih + (size_t)(d + 256) * 256);

    for (int k4 = 0; k4 < 64; ++k4) {
        float4 wr = wir4[k4], wz = wiz4[k4], wn = win4[k4];
#pragma unroll
        for (int p = 0; p < 16; ++p) {
            int nl = sg + 2*p;
            float4 i4 = *(const float4*)&As[nl][k4 * 4];
            cr[p] += dot4(wr, i4);
            cz[p] += dot4(wz, i4);
            cn[p] += dot4(wn, i4);
        }
    }

    const float4* ur4 = (const float4*)(whh + (size_t)(d      ) * D_);
    const float4* uz4 = (const float4*)(whh + (size_t)(d + 128) * D_);
    const float4* un4 = (const float4*)(whh + (size_t)(d + 256) * D_);
    const float* hidb = hidden + (size_t)b * N_ * D_ + (size_t)n0 * D_;

    for (int k4 = 0; k4 < 32; ++k4) {
        float4 ur = ur4[k4], uz = uz4[k4], un = un4[k4];
#pragma unroll
        for (int p = 0; p < 16; ++p) {
            int nl = sg + 2*p;
            float4 h4 = *(const float4*)&hidb[(size_t)nl * D_ + k4 * 4];
            cr[p]  += dot4(ur, h4);
            cz[p]  += dot4(uz, h4);
            chn[p] += dot4(un, h4);
        }
    }

#pragma unroll
    for (int p = 0; p < 16; ++p) {
        int nl = sg + 2*p;
        float hv = hidb[(size_t)nl * D_ + d];
        float r  = sigm(cr[p]);
        float z  = sigm(cz[p]);
        float ng = fast_tanh(cn[p] + r * chn[p]);
        out[(size_t)b * N_ * D_ + (size_t)(n0 + nl) * D_ + d] = (1.0f - z) * hv + z * ng;
    }
}

// ---------------------------------------------------------------------------
extern "C" void kernel_launch(void* const* d_in, const int* in_sizes, int n_in,
                              void* d_out, int out_size, void* d_ws, size_t ws_size,
                              hipStream_t stream) {
    const float* A     = (const float*)d_in[0];
    const float* hidden= (const float*)d_in[1];
    const float* mi    = (const float*)d_in[2];
    const float* xa    = (const float*)d_in[3];
    const int*   len   = (const int*)  d_in[4];
    const float* gwih  = (const float*)d_in[5];
    const float* gwhh  = (const float*)d_in[6];
    const float* gbih  = (const float*)d_in[7];
    const float* gbhh  = (const float*)d_in[8];
    const float* wih   = (const float*)d_in[9];
    const float* whh   = (const float*)d_in[10];
    const float* bih   = (const float*)d_in[11];
    const float* bhh   = (const float*)d_in[12];
    const float* biah  = (const float*)d_in[13];
    const float* bioh  = (const float*)d_in[14];
    const float* w_in  = (const float*)d_in[15];
    const float* b_in  = (const float*)d_in[16];
    const float* w_out = (const float*)d_in[17];
    const float* b_out = (const float*)d_in[18];

    float* out = (float*)d_out;
    float* mh   = out;                              // [M,D] == out size
    float* hin  = (float*)d_ws;                     // [M, D]
    float* hout = hin + (size_t)M_ * D_;            // [M, D]

    k1_gru_mfma<<<M_ / 32, 256, 0, stream>>>(xa, len, gwih, gwhh, gbih, gbhh, mh);
    k2_edges<<<M_ / 16, 256, 0, stream>>>(mi, mh, w_in, b_in, w_out, b_out, hin, hout);
    k3_gate <<<B_ * 4,  256, 0, stream>>>(A, hidden, hin, hout, wih, whh, bih, bhh,
                                          biah, bioh, out);
}

// Round 3
// 383.992 us; speedup vs baseline: 17.7008x; 2.2886x over previous
//
#include <hip/hip_runtime.h>
#include <math.h>

#define B_ 256
#define E_ 128
#define N_ 128
#define T_ 20
#define D_ 128
#define M_ (B_*E_)   // 32768 sequences

typedef __attribute__((ext_vector_type(8))) short bf16x8;
typedef __attribute__((ext_vector_type(4))) short s16x4;
typedef __attribute__((ext_vector_type(4))) float f32x4;

__device__ __forceinline__ float sigm(float x) { return 1.0f / (1.0f + __expf(-x)); }
__device__ __forceinline__ float fast_tanh(float x) {
    float e = __expf(2.f * x);
    return 1.f - 2.f / (e + 1.f);
}
__device__ __forceinline__ short f2bf(float f) {   // RNE float->bf16
    unsigned u = __builtin_bit_cast(unsigned, f);
    u += 0x7fffu + ((u >> 16) & 1u);
    return (short)(u >> 16);
}
__device__ __forceinline__ bf16x8 cvt8(const float* __restrict__ p) {
    float4 u = *(const float4*)p;
    float4 v = *(const float4*)(p + 4);
    bf16x8 f;
    f[0]=f2bf(u.x); f[1]=f2bf(u.y); f[2]=f2bf(u.z); f[3]=f2bf(u.w);
    f[4]=f2bf(v.x); f[5]=f2bf(v.y); f[6]=f2bf(v.z); f[7]=f2bf(v.w);
    return f;
}

// [rows][32k] bf16 slice, 64 B/row; chunk-XOR swizzle: 16 consecutive rows at
// fixed chunk -> 8 bank-groups x 2-way (free).
#define SLADDR(row, chunk) ((row) * 64 + ((((chunk) ^ ((row) >> 1)) & 3) << 4))

// ---------------------------------------------------------------------------
// K1: persistent MFMA micro-GRU (unchanged from round 2; verified). 32 seqs
// per block, 4 waves, T=20 steps, h in fp32 regs, weights pinned as bf16 frags.
// ---------------------------------------------------------------------------
__global__ __launch_bounds__(256, 1) void k1_gru_mfma(
    const float* __restrict__ xa, const int* __restrict__ len,
    const float* __restrict__ wih, const float* __restrict__ whh,
    const float* __restrict__ bih, const float* __restrict__ bhh,
    float* __restrict__ mh)
{
    __shared__ __align__(16) char inT[32 * 512];

    const int tid = threadIdx.x;
    const int l   = tid & 63;
    const int w   = tid >> 6;
    const int l15 = l & 15;
    const int l4  = l >> 4;
    const int m0  = blockIdx.x * 32;

    bf16x8 wf[2][6][4];
    {
        const int kg = l4 * 8;
#pragma unroll
        for (int s = 0; s < 2; ++s) {
            const float* W = s ? whh : wih;
#pragma unroll
            for (int jj = 0; jj < 6; ++jj) {
                int grow = (jj >> 1) * 128 + (w * 2 + (jj & 1)) * 16 + l15;
#pragma unroll
                for (int kt = 0; kt < 4; ++kt) {
                    wf[s][jj][kt] = cvt8(W + (size_t)grow * 128 + kt * 32 + kg);
                }
            }
        }
    }

    float brz[2], bzz[2], bin_[2], bhn_[2];
#pragma unroll
    for (int p = 0; p < 2; ++p) {
        int d = (w * 2 + p) * 16 + l15;
        brz[p] = bih[d]       + bhh[d];
        bzz[p] = bih[128 + d] + bhh[128 + d];
        bin_[p]= bih[256 + d];
        bhn_[p]= bhh[256 + d];
    }
    int lenv[8];
#pragma unroll
    for (int mt = 0; mt < 2; ++mt)
#pragma unroll
        for (int r = 0; r < 4; ++r)
            lenv[mt * 4 + r] = len[m0 + mt * 16 + l4 * 4 + r];

    float hm[2][2][4];
#pragma unroll
    for (int mt = 0; mt < 2; ++mt)
#pragma unroll
        for (int p = 0; p < 2; ++p)
#pragma unroll
            for (int r = 0; r < 4; ++r) hm[mt][p][r] = 0.f;

    const int sr = tid >> 3;
    const int sc = (tid & 7) * 16;
    const float* xbase = xa + (size_t)(m0 + sr) * (T_ * D_) + sc;
    float4 xp0, xp1, xp2, xp3;
    { const float4* p = (const float4*)xbase; xp0=p[0]; xp1=p[1]; xp2=p[2]; xp3=p[3]; }

#pragma unroll 1
    for (int t = 0; t < T_; ++t) {
        {
            bf16x8 c0, c1;
            c0[0]=f2bf(xp0.x); c0[1]=f2bf(xp0.y); c0[2]=f2bf(xp0.z); c0[3]=f2bf(xp0.w);
            c0[4]=f2bf(xp1.x); c0[5]=f2bf(xp1.y); c0[6]=f2bf(xp1.z); c0[7]=f2bf(xp1.w);
            c1[0]=f2bf(xp2.x); c1[1]=f2bf(xp2.y); c1[2]=f2bf(xp2.z); c1[3]=f2bf(xp2.w);
            c1[4]=f2bf(xp3.x); c1[5]=f2bf(xp3.y); c1[6]=f2bf(xp3.z); c1[7]=f2bf(xp3.w);
            int cb0 = sc * 2;
            int sw  = (sr & 7) << 4;
            *(bf16x8*)(inT + sr * 512 + ((cb0     ) ^ sw)) = c0;
            *(bf16x8*)(inT + sr * 512 + ((cb0 + 16) ^ sw)) = c1;
        }
        __syncthreads();

        if (t + 1 < T_) {
            const float4* p = (const float4*)(xbase + (t + 1) * D_);
            xp0 = p[0]; xp1 = p[1]; xp2 = p[2]; xp3 = p[3];
        }

        f32x4 ax[2][6], ah[2][6];
#pragma unroll
        for (int mt = 0; mt < 2; ++mt)
#pragma unroll
            for (int jj = 0; jj < 6; ++jj) {
                ax[mt][jj] = (f32x4){0.f,0.f,0.f,0.f};
                ah[mt][jj] = (f32x4){0.f,0.f,0.f,0.f};
            }

#pragma unroll
        for (int kt = 0; kt < 4; ++kt) {
            int cb = kt * 64 + l4 * 16;
            int r0 = l15, r1 = 16 + l15;
            bf16x8 a0 = *(const bf16x8*)(inT + r0 * 512 + (cb ^ ((r0 & 7) << 4)));
            bf16x8 a1 = *(const bf16x8*)(inT + r1 * 512 + (cb ^ ((r1 & 7) << 4)));
#pragma unroll
            for (int jj = 0; jj < 6; ++jj) {
                ax[0][jj] = __builtin_amdgcn_mfma_f32_16x16x32_bf16(a0, wf[0][jj][kt], ax[0][jj], 0, 0, 0);
                ax[1][jj] = __builtin_amdgcn_mfma_f32_16x16x32_bf16(a1, wf[0][jj][kt], ax[1][jj], 0, 0, 0);
            }
        }
        if (t > 0) {
#pragma unroll
            for (int kt = 0; kt < 4; ++kt) {
                int cb = 256 + kt * 64 + l4 * 16;
                int r0 = l15, r1 = 16 + l15;
                bf16x8 a0 = *(const bf16x8*)(inT + r0 * 512 + (cb ^ ((r0 & 7) << 4)));
                bf16x8 a1 = *(const bf16x8*)(inT + r1 * 512 + (cb ^ ((r1 & 7) << 4)));
#pragma unroll
                for (int jj = 0; jj < 6; ++jj) {
                    ah[0][jj] = __builtin_amdgcn_mfma_f32_16x16x32_bf16(a0, wf[1][jj][kt], ah[0][jj], 0, 0, 0);
                    ah[1][jj] = __builtin_amdgcn_mfma_f32_16x16x32_bf16(a1, wf[1][jj][kt], ah[1][jj], 0, 0, 0);
                }
            }
        }

        float hb[2][2][4];
#pragma unroll
        for (int mt = 0; mt < 2; ++mt)
#pragma unroll
            for (int p = 0; p < 2; ++p)
#pragma unroll
                for (int r = 0; r < 4; ++r) {
                    float gr = ax[mt][0 + p][r] + ah[mt][0 + p][r] + brz[p];
                    float gz = ax[mt][2 + p][r] + ah[mt][2 + p][r] + bzz[p];
                    float gi = ax[mt][4 + p][r] + bin_[p];
                    float gh = ah[mt][4 + p][r] + bhn_[p];
                    float rr = sigm(gr), zz = sigm(gz);
                    float nn = fast_tanh(gi + rr * gh);
                    float hold = hm[mt][p][r];
                    float hnew = (1.f - zz) * nn + zz * hold;
                    hnew = (t < lenv[mt * 4 + r]) ? hnew : hold;
                    hm[mt][p][r] = hnew;
                    hb[mt][p][r] = hnew;
                }

        __syncthreads();

#pragma unroll
        for (int mt = 0; mt < 2; ++mt)
#pragma unroll
            for (int p = 0; p < 2; ++p)
#pragma unroll
                for (int r = 0; r < 4; ++r) {
                    int row = mt * 16 + l4 * 4 + r;
                    int cb  = 256 + (w * 2 + p) * 32 + l15 * 2;
                    *(short*)(inT + row * 512 + (cb ^ ((row & 7) << 4))) = f2bf(hb[mt][p][r]);
                }
    }

#pragma unroll
    for (int mt = 0; mt < 2; ++mt)
#pragma unroll
        for (int p = 0; p < 2; ++p)
#pragma unroll
            for (int r = 0; r < 4; ++r) {
                int m = m0 + mt * 16 + l4 * 4 + r;
                int d = (w * 2 + p) * 16 + l15;
                mh[(size_t)m * D_ + d] = hm[mt][p][r];
            }
}

// ---------------------------------------------------------------------------
// K2 (MFMA): [mi|mh] (32768x256) @ [w_in;w_out]^T -> h_ioT[b][j][e] bf16.
// One batch (128 rows) per block, 8 waves (4 row x 2 col), K=256.
// Output written TRANSPOSED so k3a's B-stage is a straight copy.
// ---------------------------------------------------------------------------
__global__ __launch_bounds__(512) void k2_mfma(
    const float* __restrict__ mi, const float* __restrict__ mh,
    const float* __restrict__ w_in, const float* __restrict__ b_in,
    const float* __restrict__ w_out, const float* __restrict__ b_out,
    short* __restrict__ hioT)     // [B][256][128] bf16 (in d_out)
{
    __shared__ __align__(16) char As[128 * 64];
    __shared__ __align__(16) char Bs[256 * 64];

    const int tid = threadIdx.x;
    const int l = tid & 63, w = tid >> 6;
    const int l15 = l & 15, l4 = l >> 4;
    const int wr = w >> 1, wc = w & 1;
    const int b  = blockIdx.x;
    const int m0 = b * 128;

    float bj[8];
#pragma unroll
    for (int cf = 0; cf < 8; ++cf) {
        int j = wc * 128 + cf * 16 + l15;
        bj[cf] = (j < 128) ? b_in[j] : b_out[j - 128];
    }

    f32x4 acc[2][8];
#pragma unroll
    for (int rf = 0; rf < 2; ++rf)
#pragma unroll
        for (int cf = 0; cf < 8; ++cf) acc[rf][cf] = (f32x4){0.f,0.f,0.f,0.f};

    const int srow = tid >> 2, sc4 = tid & 3;
    const int brow = tid >> 1, bh  = tid & 1;

#pragma unroll 1
    for (int kt = 0; kt < 8; ++kt) {
        {
            const float* src = (kt < 4)
                ? (mi + (size_t)(m0 + srow) * 128 + kt * 32 + sc4 * 8)
                : (mh + (size_t)(m0 + srow) * 128 + (kt - 4) * 32 + sc4 * 8);
            *(bf16x8*)(As + SLADDR(srow, sc4)) = cvt8(src);
        }
        {
            const float* wsrc = (brow < 128)
                ? (w_in  + (size_t)brow * 256 + kt * 32 + bh * 16)
                : (w_out + (size_t)(brow - 128) * 256 + kt * 32 + bh * 16);
            *(bf16x8*)(Bs + SLADDR(brow, bh * 2    )) = cvt8(wsrc);
            *(bf16x8*)(Bs + SLADDR(brow, bh * 2 + 1)) = cvt8(wsrc + 8);
        }
        __syncthreads();

        bf16x8 af[2], bfr[8];
#pragma unroll
        for (int rf = 0; rf < 2; ++rf)
            af[rf] = *(const bf16x8*)(As + SLADDR(wr * 32 + rf * 16 + l15, l4));
#pragma unroll
        for (int cf = 0; cf < 8; ++cf)
            bfr[cf] = *(const bf16x8*)(Bs + SLADDR(wc * 128 + cf * 16 + l15, l4));
#pragma unroll
        for (int rf = 0; rf < 2; ++rf)
#pragma unroll
            for (int cf = 0; cf < 8; ++cf)
                acc[rf][cf] = __builtin_amdgcn_mfma_f32_16x16x32_bf16(af[rf], bfr[cf], acc[rf][cf], 0, 0, 0);
        __syncthreads();
    }

#pragma unroll
    for (int rf = 0; rf < 2; ++rf)
#pragma unroll
        for (int cf = 0; cf < 8; ++cf) {
            int j  = wc * 128 + cf * 16 + l15;
            int e0 = wr * 32 + rf * 16 + l4 * 4;
            s16x4 s;
#pragma unroll
            for (int r = 0; r < 4; ++r) s[r] = f2bf(acc[rf][cf][r] + bj[cf]);
            *(s16x4*)(hioT + ((size_t)b * 256 + j) * 128 + e0) = s;
        }
}

// ---------------------------------------------------------------------------
// K3a (MFMA): per-batch einsum. inputs[n][j] = sum_e A[b][n][e or 128+e] *
// hioT[b][j][e] + bias. Col-wave 0 -> input_in (A_in), col-wave 1 -> input_out.
// ---------------------------------------------------------------------------
__global__ __launch_bounds__(512) void k3a_einsum(
    const float* __restrict__ A, const short* __restrict__ hioT,
    const float* __restrict__ b_iah, const float* __restrict__ b_ioh,
    short* __restrict__ inputs)    // [M][256] bf16 (ws)
{
    __shared__ __align__(16) char As0[128 * 64];
    __shared__ __align__(16) char As1[128 * 64];
    __shared__ __align__(16) char Bs [256 * 64];

    const int tid = threadIdx.x;
    const int l = tid & 63, w = tid >> 6;
    const int l15 = l & 15, l4 = l >> 4;
    const int wr = w >> 1, wc = w & 1;
    const int b  = blockIdx.x;

    float bj[8];
#pragma unroll
    for (int cf = 0; cf < 8; ++cf) {
        int j = wc * 128 + cf * 16 + l15;
        bj[cf] = (j < 128) ? b_iah[j] : b_ioh[j - 128];
    }

    f32x4 acc[2][8];
#pragma unroll
    for (int rf = 0; rf < 2; ++rf)
#pragma unroll
        for (int cf = 0; cf < 8; ++cf) acc[rf][cf] = (f32x4){0.f,0.f,0.f,0.f};

    const int srow = tid >> 2, sc4 = tid & 3;
    const int brow = tid >> 1, bh  = tid & 1;
    const float* Ab = A + (size_t)b * 128 * 256;

#pragma unroll 1
    for (int kt = 0; kt < 4; ++kt) {
        *(bf16x8*)(As0 + SLADDR(srow, sc4)) = cvt8(Ab + (size_t)srow * 256 +       kt * 32 + sc4 * 8);
        *(bf16x8*)(As1 + SLADDR(srow, sc4)) = cvt8(Ab + (size_t)srow * 256 + 128 + kt * 32 + sc4 * 8);
        {
            const short* hs = hioT + ((size_t)b * 256 + brow) * 128 + kt * 32 + bh * 16;
            *(bf16x8*)(Bs + SLADDR(brow, bh * 2    )) = *(const bf16x8*)hs;
            *(bf16x8*)(Bs + SLADDR(brow, bh * 2 + 1)) = *(const bf16x8*)(hs + 8);
        }
        __syncthreads();

        const char* Asel = wc ? As1 : As0;
        bf16x8 af[2], bfr[8];
#pragma unroll
        for (int rf = 0; rf < 2; ++rf)
            af[rf] = *(const bf16x8*)(Asel + SLADDR(wr * 32 + rf * 16 + l15, l4));
#pragma unroll
        for (int cf = 0; cf < 8; ++cf)
            bfr[cf] = *(const bf16x8*)(Bs + SLADDR(wc * 128 + cf * 16 + l15, l4));
#pragma unroll
        for (int rf = 0; rf < 2; ++rf)
#pragma unroll
            for (int cf = 0; cf < 8; ++cf)
                acc[rf][cf] = __builtin_amdgcn_mfma_f32_16x16x32_bf16(af[rf], bfr[cf], acc[rf][cf], 0, 0, 0);
        __syncthreads();
    }

#pragma unroll
    for (int rf = 0; rf < 2; ++rf)
#pragma unroll
        for (int cf = 0; cf < 8; ++cf) {
            int j = wc * 128 + cf * 16 + l15;
#pragma unroll
            for (int r = 0; r < 4; ++r) {
                int m = b * 128 + wr * 32 + rf * 16 + l4 * 4 + r;
                inputs[(size_t)m * 256 + j] = f2bf(acc[rf][cf][r] + bj[cf]);
            }
        }
}

// ---------------------------------------------------------------------------
// K3b (MFMA): gate GEMM + epilogue. r/z gates: K=384 over [inputs|hidden];
// n gate split: i_n (K=256, inputs x w_ih) and h_n (K=128, hidden x w_hh)
// kept in separate accumulators (r multiplies only h_n). Lane-local epilogue.
// ---------------------------------------------------------------------------
__global__ __launch_bounds__(512) void k3b_gate(
    const short* __restrict__ inputs, const float* __restrict__ hidden,
    const float* __restrict__ wih, const float* __restrict__ whh,
    const float* __restrict__ bih, const float* __restrict__ bhh,
    float* __restrict__ out)
{
    __shared__ __align__(16) char As[128 * 64];
    __shared__ __align__(16) char Bs[384 * 64];

    const int tid = threadIdx.x;
    const int l = tid & 63, w = tid >> 6;
    const int l15 = l & 15, l4 = l >> 4;
    const int wr = w >> 1, wc = w & 1;
    const int m0 = blockIdx.x * 128;

    float br[4], bz[4], bi[4], bh_[4];
#pragma unroll
    for (int p = 0; p < 4; ++p) {
        int d = (wc * 4 + p) * 16 + l15;
        br[p] = bih[d]       + bhh[d];
        bz[p] = bih[128 + d] + bhh[128 + d];
        bi[p] = bih[256 + d];
        bh_[p]= bhh[256 + d];
    }

    f32x4 aR[2][4], aZ[2][4], aI[2][4], aH[2][4];
#pragma unroll
    for (int rf = 0; rf < 2; ++rf)
#pragma unroll
        for (int p = 0; p < 4; ++p) {
            aR[rf][p] = (f32x4){0.f,0.f,0.f,0.f};
            aZ[rf][p] = (f32x4){0.f,0.f,0.f,0.f};
            aI[rf][p] = (f32x4){0.f,0.f,0.f,0.f};
            aH[rf][p] = (f32x4){0.f,0.f,0.f,0.f};
        }

    const int srow = tid >> 2, sc4 = tid & 3;

#pragma unroll 1
    for (int kt = 0; kt < 12; ++kt) {
        if (kt < 8) {
            const short* src = inputs + (size_t)(m0 + srow) * 256 + kt * 32 + sc4 * 8;
            *(bf16x8*)(As + SLADDR(srow, sc4)) = *(const bf16x8*)src;
        } else {
            const float* src = hidden + (size_t)(m0 + srow) * 128 + (kt - 8) * 32 + sc4 * 8;
            *(bf16x8*)(As + SLADDR(srow, sc4)) = cvt8(src);
        }
#pragma unroll
        for (int i = 0; i < 3; ++i) {
            int c = tid + 512 * i;
            int row = c >> 2, ch = c & 3;
            const float* wsrc = (kt < 8)
                ? (wih + (size_t)row * 256 + kt * 32 + ch * 8)
                : (whh + (size_t)row * 128 + (kt - 8) * 32 + ch * 8);
            *(bf16x8*)(Bs + SLADDR(row, ch)) = cvt8(wsrc);
        }
        __syncthreads();

        bf16x8 a0 = *(const bf16x8*)(As + SLADDR(wr * 32 +      l15, l4));
        bf16x8 a1 = *(const bf16x8*)(As + SLADDR(wr * 32 + 16 + l15, l4));
#pragma unroll
        for (int p = 0; p < 4; ++p) {
            int jb = (wc * 4 + p) * 16 + l15;
            bf16x8 bR = *(const bf16x8*)(Bs + SLADDR(      jb, l4));
            bf16x8 bZ = *(const bf16x8*)(Bs + SLADDR(128 + jb, l4));
            bf16x8 bN = *(const bf16x8*)(Bs + SLADDR(256 + jb, l4));
            aR[0][p] = __builtin_amdgcn_mfma_f32_16x16x32_bf16(a0, bR, aR[0][p], 0, 0, 0);
            aR[1][p] = __builtin_amdgcn_mfma_f32_16x16x32_bf16(a1, bR, aR[1][p], 0, 0, 0);
            aZ[0][p] = __builtin_amdgcn_mfma_f32_16x16x32_bf16(a0, bZ, aZ[0][p], 0, 0, 0);
            aZ[1][p] = __builtin_amdgcn_mfma_f32_16x16x32_bf16(a1, bZ, aZ[1][p], 0, 0, 0);
            if (kt < 8) {
                aI[0][p] = __builtin_amdgcn_mfma_f32_16x16x32_bf16(a0, bN, aI[0][p], 0, 0, 0);
                aI[1][p] = __builtin_amdgcn_mfma_f32_16x16x32_bf16(a1, bN, aI[1][p], 0, 0, 0);
            } else {
                aH[0][p] = __builtin_amdgcn_mfma_f32_16x16x32_bf16(a0, bN, aH[0][p], 0, 0, 0);
                aH[1][p] = __builtin_amdgcn_mfma_f32_16x16x32_bf16(a1, bN, aH[1][p], 0, 0, 0);
            }
        }
        __syncthreads();
    }

#pragma unroll
    for (int rf = 0; rf < 2; ++rf)
#pragma unroll
        for (int p = 0; p < 4; ++p) {
            int d = (wc * 4 + p) * 16 + l15;
#pragma unroll
            for (int r = 0; r < 4; ++r) {
                int m = m0 + wr * 32 + rf * 16 + l4 * 4 + r;
                float hv = hidden[(size_t)m * 128 + d];
                float rg = sigm(aR[rf][p][r] + br[p]);
                float zg = sigm(aZ[rf][p][r] + bz[p]);
                float ng = fast_tanh(aI[rf][p][r] + bi[p] + rg * (aH[rf][p][r] + bh_[p]));
                out[(size_t)m * 128 + d] = (1.f - zg) * hv + zg * ng;
            }
        }
}

// ---------------------------------------------------------------------------
extern "C" void kernel_launch(void* const* d_in, const int* in_sizes, int n_in,
                              void* d_out, int out_size, void* d_ws, size_t ws_size,
                              hipStream_t stream) {
    const float* A     = (const float*)d_in[0];
    const float* hidden= (const float*)d_in[1];
    const float* mi    = (const float*)d_in[2];
    const float* xa    = (const float*)d_in[3];
    const int*   len   = (const int*)  d_in[4];
    const float* gwih  = (const float*)d_in[5];
    const float* gwhh  = (const float*)d_in[6];
    const float* gbih  = (const float*)d_in[7];
    const float* gbhh  = (const float*)d_in[8];
    const float* wih   = (const float*)d_in[9];
    const float* whh   = (const float*)d_in[10];
    const float* bih   = (const float*)d_in[11];
    const float* bhh   = (const float*)d_in[12];
    const float* biah  = (const float*)d_in[13];
    const float* bioh  = (const float*)d_in[14];
    const float* w_in  = (const float*)d_in[15];
    const float* b_in  = (const float*)d_in[16];
    const float* w_out = (const float*)d_in[17];
    const float* b_out = (const float*)d_in[18];

    float* out = (float*)d_out;
    // ws layout (33.55 MB total, same footprint as round 1):
    //   [0, 16.78 MB):  mh fp32 [M][128]          (k1 -> k2)
    //   [16.78, 33.55): inputs bf16 [M][256]      (k3a -> k3b)
    // d_out doubles as h_ioT bf16 [B][256][128]   (k2 -> k3a), overwritten by k3b.
    float* mh     = (float*)d_ws;
    short* inputs = (short*)((char*)d_ws + (size_t)M_ * D_ * 4);
    short* hioT   = (short*)d_out;

    k1_gru_mfma<<<M_ / 32, 256, 0, stream>>>(xa, len, gwih, gwhh, gbih, gbhh, mh);
    k2_mfma    <<<B_,      512, 0, stream>>>(mi, mh, w_in, b_in, w_out, b_out, hioT);
    k3a_einsum <<<B_,      512, 0, stream>>>(A, hioT, biah, bioh, inputs);
    k3b_gate   <<<M_/128,  512, 0, stream>>>(inputs, hidden, wih, whh, bih, bhh, out);
}

// Round 4
// 325.780 us; speedup vs baseline: 20.8637x; 1.1787x over previous
//
#include <hip/hip_runtime.h>
#include <math.h>

#define B_ 256
#define E_ 128
#define N_ 128
#define T_ 20
#define D_ 128
#define M_ (B_*E_)   // 32768 sequences

typedef __attribute__((ext_vector_type(8))) short bf16x8;
typedef __attribute__((ext_vector_type(4))) short s16x4;
typedef __attribute__((ext_vector_type(4))) float f32x4;

__device__ __forceinline__ float sigm(float x) { return 1.0f / (1.0f + __expf(-x)); }
__device__ __forceinline__ float fast_tanh(float x) {
    float e = __expf(2.f * x);
    return 1.f - 2.f / (e + 1.f);
}
__device__ __forceinline__ short f2bf(float f) {   // RNE float->bf16
    unsigned u = __builtin_bit_cast(unsigned, f);
    u += 0x7fffu + ((u >> 16) & 1u);
    return (short)(u >> 16);
}
__device__ __forceinline__ bf16x8 cvt8(const float* __restrict__ p) {
    float4 u = *(const float4*)p;
    float4 v = *(const float4*)(p + 4);
    bf16x8 f;
    f[0]=f2bf(u.x); f[1]=f2bf(u.y); f[2]=f2bf(u.z); f[3]=f2bf(u.w);
    f[4]=f2bf(v.x); f[5]=f2bf(v.y); f[6]=f2bf(v.z); f[7]=f2bf(v.w);
    return f;
}

// [rows][32k] bf16 slice, 64 B/row; chunk-XOR swizzle (k2/k3 kernels).
#define SLADDR(row, chunk) ((row) * 64 + ((((chunk) ^ ((row) >> 1)) & 3) << 4))

// [32 rows][128 cols bf16] tile, 256 B/row, byte-XOR swizzle (k1).
__device__ __forceinline__ bf16x8 t_frag(const char* base, int row, int cb) {
    return *(const bf16x8*)(base + row * 256 + (cb ^ ((row & 7) << 4)));
}

// ---------------------------------------------------------------------------
// K1: persistent MFMA micro-GRU, 8 waves / 512 threads, 32 seqs per block.
// Wave w owns output d-tile w (cols w*16..w*16+15) -> 24 weight frags (96
// VGPR) per wave, r/z X+H phases share accumulators. X and H tiles are
// double-buffered in LDS -> ONE barrier per timestep (write side targets the
// [nxt] buffers whose readers finished before the previous barrier).
// ---------------------------------------------------------------------------
__global__ __launch_bounds__(512, 2) void k1_gru_mfma(
    const float* __restrict__ xa, const int* __restrict__ len,
    const float* __restrict__ wih, const float* __restrict__ whh,
    const float* __restrict__ bih, const float* __restrict__ bhh,
    float* __restrict__ mh)
{
    __shared__ __align__(16) char Xb[2][32 * 256];  // [32][128] bf16 each
    __shared__ __align__(16) char Hb[2][32 * 256];

    const int tid = threadIdx.x;
    const int l   = tid & 63;
    const int w   = tid >> 6;     // wave id 0..7 = d-tile
    const int l15 = l & 15;
    const int l4  = l >> 4;
    const int m0  = blockIdx.x * 32;

    // ---- weight B-frags: wf[s][g][kt], s=0:w_ih 1:w_hh, g=0:r 1:z 2:n ----
    // lane holds W[g*128 + w*16 + l15][kt*32 + l4*8 .. +7]
    bf16x8 wf[2][3][4];
#pragma unroll
    for (int s = 0; s < 2; ++s) {
        const float* W = s ? whh : wih;
#pragma unroll
        for (int g = 0; g < 3; ++g) {
            int grow = g * 128 + w * 16 + l15;
#pragma unroll
            for (int kt = 0; kt < 4; ++kt)
                wf[s][g][kt] = cvt8(W + (size_t)grow * 128 + kt * 32 + l4 * 8);
        }
    }

    // ---- biases (lane-local, d = w*16 + l15) ----
    const int dcol = w * 16 + l15;
    const float brz = bih[dcol]       + bhh[dcol];
    const float bzz = bih[128 + dcol] + bhh[128 + dcol];
    const float bin_= bih[256 + dcol];
    const float bhn_= bhh[256 + dcol];

    int lenv[8];
#pragma unroll
    for (int mt = 0; mt < 2; ++mt)
#pragma unroll
        for (int r = 0; r < 4; ++r)
            lenv[mt * 4 + r] = len[m0 + mt * 16 + l4 * 4 + r];

    float hm[2][4];
#pragma unroll
    for (int mt = 0; mt < 2; ++mt)
#pragma unroll
        for (int r = 0; r < 4; ++r) hm[mt][r] = 0.f;

    // ---- X staging: thread -> (row sr, 8 cols at sc) ----
    const int sr = tid >> 4;          // 0..31
    const int sc = (tid & 15) * 8;    // col in elems
    const float* xbase = xa + (size_t)(m0 + sr) * (T_ * D_) + sc;

    // prologue: stage X_0, prefetch X_1
    float4 xp0, xp1;
    {
        const float4* p = (const float4*)xbase;
        float4 a = p[0], b = p[1];
        bf16x8 c;
        c[0]=f2bf(a.x); c[1]=f2bf(a.y); c[2]=f2bf(a.z); c[3]=f2bf(a.w);
        c[4]=f2bf(b.x); c[5]=f2bf(b.y); c[6]=f2bf(b.z); c[7]=f2bf(b.w);
        *(bf16x8*)(Xb[0] + sr * 256 + ((sc * 2) ^ ((sr & 7) << 4))) = c;
        const float4* q = (const float4*)(xbase + D_);
        xp0 = q[0]; xp1 = q[1];
    }
    __syncthreads();

#pragma unroll 1
    for (int t = 0; t < T_; ++t) {
        const int cur = t & 1;
        const char* Xc = Xb[cur];
        const char* Hc = Hb[cur];

        f32x4 aR[2], aZ[2], aI[2], aH[2];
#pragma unroll
        for (int mt = 0; mt < 2; ++mt) {
            aR[mt] = (f32x4){0.f,0.f,0.f,0.f};
            aZ[mt] = (f32x4){0.f,0.f,0.f,0.f};
            aI[mt] = (f32x4){0.f,0.f,0.f,0.f};
            aH[mt] = (f32x4){0.f,0.f,0.f,0.f};
        }

        // X phase
#pragma unroll
        for (int kt = 0; kt < 4; ++kt) {
            int cb = kt * 64 + l4 * 16;
#pragma unroll
            for (int mt = 0; mt < 2; ++mt) {
                bf16x8 a = t_frag(Xc, mt * 16 + l15, cb);
                aR[mt] = __builtin_amdgcn_mfma_f32_16x16x32_bf16(a, wf[0][0][kt], aR[mt], 0, 0, 0);
                aZ[mt] = __builtin_amdgcn_mfma_f32_16x16x32_bf16(a, wf[0][1][kt], aZ[mt], 0, 0, 0);
                aI[mt] = __builtin_amdgcn_mfma_f32_16x16x32_bf16(a, wf[0][2][kt], aI[mt], 0, 0, 0);
            }
        }
        // H phase (skip at t=0: h=0)
        if (t > 0) {
#pragma unroll
            for (int kt = 0; kt < 4; ++kt) {
                int cb = kt * 64 + l4 * 16;
#pragma unroll
                for (int mt = 0; mt < 2; ++mt) {
                    bf16x8 a = t_frag(Hc, mt * 16 + l15, cb);
                    aR[mt] = __builtin_amdgcn_mfma_f32_16x16x32_bf16(a, wf[1][0][kt], aR[mt], 0, 0, 0);
                    aZ[mt] = __builtin_amdgcn_mfma_f32_16x16x32_bf16(a, wf[1][1][kt], aZ[mt], 0, 0, 0);
                    aH[mt] = __builtin_amdgcn_mfma_f32_16x16x32_bf16(a, wf[1][2][kt], aH[mt], 0, 0, 0);
                }
            }
        }

        // epilogue (lane-local): gates + h update
#pragma unroll
        for (int mt = 0; mt < 2; ++mt)
#pragma unroll
            for (int r = 0; r < 4; ++r) {
                float rr = sigm(aR[mt][r] + brz);
                float zz = sigm(aZ[mt][r] + bzz);
                float nn = fast_tanh(aI[mt][r] + bin_ + rr * (aH[mt][r] + bhn_));
                float hold = hm[mt][r];
                float hnew = (1.f - zz) * nn + zz * hold;
                hm[mt][r] = (t < lenv[mt * 4 + r]) ? hnew : hold;
            }

        // write h_{t+1} to Hb[nxt]; stage X_{t+1}; prefetch X_{t+2}
        const int nxt = cur ^ 1;
        if (t + 1 < T_) {
#pragma unroll
            for (int mt = 0; mt < 2; ++mt)
#pragma unroll
                for (int r = 0; r < 4; ++r) {
                    int row = mt * 16 + l4 * 4 + r;
                    *(short*)(Hb[nxt] + row * 256 + ((dcol * 2) ^ ((row & 7) << 4))) = f2bf(hm[mt][r]);
                }
            bf16x8 c;
            c[0]=f2bf(xp0.x); c[1]=f2bf(xp0.y); c[2]=f2bf(xp0.z); c[3]=f2bf(xp0.w);
            c[4]=f2bf(xp1.x); c[5]=f2bf(xp1.y); c[6]=f2bf(xp1.z); c[7]=f2bf(xp1.w);
            *(bf16x8*)(Xb[nxt] + sr * 256 + ((sc * 2) ^ ((sr & 7) << 4))) = c;
            if (t + 2 < T_) {
                const float4* q = (const float4*)(xbase + (t + 2) * D_);
                xp0 = q[0]; xp1 = q[1];
            }
            __syncthreads();
        }
    }

    // final h -> mh (fp32)
#pragma unroll
    for (int mt = 0; mt < 2; ++mt)
#pragma unroll
        for (int r = 0; r < 4; ++r) {
            int m = m0 + mt * 16 + l4 * 4 + r;
            mh[(size_t)m * D_ + dcol] = hm[mt][r];
        }
}

// ---------------------------------------------------------------------------
// K2 (MFMA): [mi|mh] (32768x256) @ [w_in;w_out]^T -> h_ioT[b][j][e] bf16.
// (unchanged from round 3)
// ---------------------------------------------------------------------------
__global__ __launch_bounds__(512) void k2_mfma(
    const float* __restrict__ mi, const float* __restrict__ mh,
    const float* __restrict__ w_in, const float* __restrict__ b_in,
    const float* __restrict__ w_out, const float* __restrict__ b_out,
    short* __restrict__ hioT)     // [B][256][128] bf16 (in d_out)
{
    __shared__ __align__(16) char As[128 * 64];
    __shared__ __align__(16) char Bs[256 * 64];

    const int tid = threadIdx.x;
    const int l = tid & 63, w = tid >> 6;
    const int l15 = l & 15, l4 = l >> 4;
    const int wr = w >> 1, wc = w & 1;
    const int b  = blockIdx.x;
    const int m0 = b * 128;

    float bj[8];
#pragma unroll
    for (int cf = 0; cf < 8; ++cf) {
        int j = wc * 128 + cf * 16 + l15;
        bj[cf] = (j < 128) ? b_in[j] : b_out[j - 128];
    }

    f32x4 acc[2][8];
#pragma unroll
    for (int rf = 0; rf < 2; ++rf)
#pragma unroll
        for (int cf = 0; cf < 8; ++cf) acc[rf][cf] = (f32x4){0.f,0.f,0.f,0.f};

    const int srow = tid >> 2, sc4 = tid & 3;
    const int brow = tid >> 1, bh  = tid & 1;

#pragma unroll 1
    for (int kt = 0; kt < 8; ++kt) {
        {
            const float* src = (kt < 4)
                ? (mi + (size_t)(m0 + srow) * 128 + kt * 32 + sc4 * 8)
                : (mh + (size_t)(m0 + srow) * 128 + (kt - 4) * 32 + sc4 * 8);
            *(bf16x8*)(As + SLADDR(srow, sc4)) = cvt8(src);
        }
        {
            const float* wsrc = (brow < 128)
                ? (w_in  + (size_t)brow * 256 + kt * 32 + bh * 16)
                : (w_out + (size_t)(brow - 128) * 256 + kt * 32 + bh * 16);
            *(bf16x8*)(Bs + SLADDR(brow, bh * 2    )) = cvt8(wsrc);
            *(bf16x8*)(Bs + SLADDR(brow, bh * 2 + 1)) = cvt8(wsrc + 8);
        }
        __syncthreads();

        bf16x8 af[2], bfr[8];
#pragma unroll
        for (int rf = 0; rf < 2; ++rf)
            af[rf] = *(const bf16x8*)(As + SLADDR(wr * 32 + rf * 16 + l15, l4));
#pragma unroll
        for (int cf = 0; cf < 8; ++cf)
            bfr[cf] = *(const bf16x8*)(Bs + SLADDR(wc * 128 + cf * 16 + l15, l4));
#pragma unroll
        for (int rf = 0; rf < 2; ++rf)
#pragma unroll
            for (int cf = 0; cf < 8; ++cf)
                acc[rf][cf] = __builtin_amdgcn_mfma_f32_16x16x32_bf16(af[rf], bfr[cf], acc[rf][cf], 0, 0, 0);
        __syncthreads();
    }

#pragma unroll
    for (int rf = 0; rf < 2; ++rf)
#pragma unroll
        for (int cf = 0; cf < 8; ++cf) {
            int j  = wc * 128 + cf * 16 + l15;
            int e0 = wr * 32 + rf * 16 + l4 * 4;
            s16x4 s;
#pragma unroll
            for (int r = 0; r < 4; ++r) s[r] = f2bf(acc[rf][cf][r] + bj[cf]);
            *(s16x4*)(hioT + ((size_t)b * 256 + j) * 128 + e0) = s;
        }
}

// ---------------------------------------------------------------------------
// K3a (MFMA): per-batch einsum. (unchanged from round 3)
// ---------------------------------------------------------------------------
__global__ __launch_bounds__(512) void k3a_einsum(
    const float* __restrict__ A, const short* __restrict__ hioT,
    const float* __restrict__ b_iah, const float* __restrict__ b_ioh,
    short* __restrict__ inputs)    // [M][256] bf16 (ws)
{
    __shared__ __align__(16) char As0[128 * 64];
    __shared__ __align__(16) char As1[128 * 64];
    __shared__ __align__(16) char Bs [256 * 64];

    const int tid = threadIdx.x;
    const int l = tid & 63, w = tid >> 6;
    const int l15 = l & 15, l4 = l >> 4;
    const int wr = w >> 1, wc = w & 1;
    const int b  = blockIdx.x;

    float bj[8];
#pragma unroll
    for (int cf = 0; cf < 8; ++cf) {
        int j = wc * 128 + cf * 16 + l15;
        bj[cf] = (j < 128) ? b_iah[j] : b_ioh[j - 128];
    }

    f32x4 acc[2][8];
#pragma unroll
    for (int rf = 0; rf < 2; ++rf)
#pragma unroll
        for (int cf = 0; cf < 8; ++cf) acc[rf][cf] = (f32x4){0.f,0.f,0.f,0.f};

    const int srow = tid >> 2, sc4 = tid & 3;
    const int brow = tid >> 1, bh  = tid & 1;
    const float* Ab = A + (size_t)b * 128 * 256;

#pragma unroll 1
    for (int kt = 0; kt < 4; ++kt) {
        *(bf16x8*)(As0 + SLADDR(srow, sc4)) = cvt8(Ab + (size_t)srow * 256 +       kt * 32 + sc4 * 8);
        *(bf16x8*)(As1 + SLADDR(srow, sc4)) = cvt8(Ab + (size_t)srow * 256 + 128 + kt * 32 + sc4 * 8);
        {
            const short* hs = hioT + ((size_t)b * 256 + brow) * 128 + kt * 32 + bh * 16;
            *(bf16x8*)(Bs + SLADDR(brow, bh * 2    )) = *(const bf16x8*)hs;
            *(bf16x8*)(Bs + SLADDR(brow, bh * 2 + 1)) = *(const bf16x8*)(hs + 8);
        }
        __syncthreads();

        const char* Asel = wc ? As1 : As0;
        bf16x8 af[2], bfr[8];
#pragma unroll
        for (int rf = 0; rf < 2; ++rf)
            af[rf] = *(const bf16x8*)(Asel + SLADDR(wr * 32 + rf * 16 + l15, l4));
#pragma unroll
        for (int cf = 0; cf < 8; ++cf)
            bfr[cf] = *(const bf16x8*)(Bs + SLADDR(wc * 128 + cf * 16 + l15, l4));
#pragma unroll
        for (int rf = 0; rf < 2; ++rf)
#pragma unroll
            for (int cf = 0; cf < 8; ++cf)
                acc[rf][cf] = __builtin_amdgcn_mfma_f32_16x16x32_bf16(af[rf], bfr[cf], acc[rf][cf], 0, 0, 0);
        __syncthreads();
    }

#pragma unroll
    for (int rf = 0; rf < 2; ++rf)
#pragma unroll
        for (int cf = 0; cf < 8; ++cf) {
            int j = wc * 128 + cf * 16 + l15;
#pragma unroll
            for (int r = 0; r < 4; ++r) {
                int m = b * 128 + wr * 32 + rf * 16 + l4 * 4 + r;
                inputs[(size_t)m * 256 + j] = f2bf(acc[rf][cf][r] + bj[cf]);
            }
        }
}

// ---------------------------------------------------------------------------
// K3b (MFMA): gate GEMM + epilogue. (unchanged from round 3)
// ---------------------------------------------------------------------------
__global__ __launch_bounds__(512) void k3b_gate(
    const short* __restrict__ inputs, const float* __restrict__ hidden,
    const float* __restrict__ wih, const float* __restrict__ whh,
    const float* __restrict__ bih, const float* __restrict__ bhh,
    float* __restrict__ out)
{
    __shared__ __align__(16) char As[128 * 64];
    __shared__ __align__(16) char Bs[384 * 64];

    const int tid = threadIdx.x;
    const int l = tid & 63, w = tid >> 6;
    const int l15 = l & 15, l4 = l >> 4;
    const int wr = w >> 1, wc = w & 1;
    const int m0 = blockIdx.x * 128;

    float br[4], bz[4], bi[4], bh_[4];
#pragma unroll
    for (int p = 0; p < 4; ++p) {
        int d = (wc * 4 + p) * 16 + l15;
        br[p] = bih[d]       + bhh[d];
        bz[p] = bih[128 + d] + bhh[128 + d];
        bi[p] = bih[256 + d];
        bh_[p]= bhh[256 + d];
    }

    f32x4 aR[2][4], aZ[2][4], aI[2][4], aH[2][4];
#pragma unroll
    for (int rf = 0; rf < 2; ++rf)
#pragma unroll
        for (int p = 0; p < 4; ++p) {
            aR[rf][p] = (f32x4){0.f,0.f,0.f,0.f};
            aZ[rf][p] = (f32x4){0.f,0.f,0.f,0.f};
            aI[rf][p] = (f32x4){0.f,0.f,0.f,0.f};
            aH[rf][p] = (f32x4){0.f,0.f,0.f,0.f};
        }

    const int srow = tid >> 2, sc4 = tid & 3;

#pragma unroll 1
    for (int kt = 0; kt < 12; ++kt) {
        if (kt < 8) {
            const short* src = inputs + (size_t)(m0 + srow) * 256 + kt * 32 + sc4 * 8;
            *(bf16x8*)(As + SLADDR(srow, sc4)) = *(const bf16x8*)src;
        } else {
            const float* src = hidden + (size_t)(m0 + srow) * 128 + (kt - 8) * 32 + sc4 * 8;
            *(bf16x8*)(As + SLADDR(srow, sc4)) = cvt8(src);
        }
#pragma unroll
        for (int i = 0; i < 3; ++i) {
            int c = tid + 512 * i;
            int row = c >> 2, ch = c & 3;
            const float* wsrc = (kt < 8)
                ? (wih + (size_t)row * 256 + kt * 32 + ch * 8)
                : (whh + (size_t)row * 128 + (kt - 8) * 32 + ch * 8);
            *(bf16x8*)(Bs + SLADDR(row, ch)) = cvt8(wsrc);
        }
        __syncthreads();

        bf16x8 a0 = *(const bf16x8*)(As + SLADDR(wr * 32 +      l15, l4));
        bf16x8 a1 = *(const bf16x8*)(As + SLADDR(wr * 32 + 16 + l15, l4));
#pragma unroll
        for (int p = 0; p < 4; ++p) {
            int jb = (wc * 4 + p) * 16 + l15;
            bf16x8 bR = *(const bf16x8*)(Bs + SLADDR(      jb, l4));
            bf16x8 bZ = *(const bf16x8*)(Bs + SLADDR(128 + jb, l4));
            bf16x8 bN = *(const bf16x8*)(Bs + SLADDR(256 + jb, l4));
            aR[0][p] = __builtin_amdgcn_mfma_f32_16x16x32_bf16(a0, bR, aR[0][p], 0, 0, 0);
            aR[1][p] = __builtin_amdgcn_mfma_f32_16x16x32_bf16(a1, bR, aR[1][p], 0, 0, 0);
            aZ[0][p] = __builtin_amdgcn_mfma_f32_16x16x32_bf16(a0, bZ, aZ[0][p], 0, 0, 0);
            aZ[1][p] = __builtin_amdgcn_mfma_f32_16x16x32_bf16(a1, bZ, aZ[1][p], 0, 0, 0);
            if (kt < 8) {
                aI[0][p] = __builtin_amdgcn_mfma_f32_16x16x32_bf16(a0, bN, aI[0][p], 0, 0, 0);
                aI[1][p] = __builtin_amdgcn_mfma_f32_16x16x32_bf16(a1, bN, aI[1][p], 0, 0, 0);
            } else {
                aH[0][p] = __builtin_amdgcn_mfma_f32_16x16x32_bf16(a0, bN, aH[0][p], 0, 0, 0);
                aH[1][p] = __builtin_amdgcn_mfma_f32_16x16x32_bf16(a1, bN, aH[1][p], 0, 0, 0);
            }
        }
        __syncthreads();
    }

#pragma unroll
    for (int rf = 0; rf < 2; ++rf)
#pragma unroll
        for (int p = 0; p < 4; ++p) {
            int d = (wc * 4 + p) * 16 + l15;
#pragma unroll
            for (int r = 0; r < 4; ++r) {
                int m = m0 + wr * 32 + rf * 16 + l4 * 4 + r;
                float hv = hidden[(size_t)m * 128 + d];
                float rg = sigm(aR[rf][p][r] + br[p]);
                float zg = sigm(aZ[rf][p][r] + bz[p]);
                float ng = fast_tanh(aI[rf][p][r] + bi[p] + rg * (aH[rf][p][r] + bh_[p]));
                out[(size_t)m * 128 + d] = (1.f - zg) * hv + zg * ng;
            }
        }
}

// ---------------------------------------------------------------------------
extern "C" void kernel_launch(void* const* d_in, const int* in_sizes, int n_in,
                              void* d_out, int out_size, void* d_ws, size_t ws_size,
                              hipStream_t stream) {
    const float* A     = (const float*)d_in[0];
    const float* hidden= (const float*)d_in[1];
    const float* mi    = (const float*)d_in[2];
    const float* xa    = (const float*)d_in[3];
    const int*   len   = (const int*)  d_in[4];
    const float* gwih  = (const float*)d_in[5];
    const float* gwhh  = (const float*)d_in[6];
    const float* gbih  = (const float*)d_in[7];
    const float* gbhh  = (const float*)d_in[8];
    const float* wih   = (const float*)d_in[9];
    const float* whh   = (const float*)d_in[10];
    const float* bih   = (const float*)d_in[11];
    const float* bhh   = (const float*)d_in[12];
    const float* biah  = (const float*)d_in[13];
    const float* bioh  = (const float*)d_in[14];
    const float* w_in  = (const float*)d_in[15];
    const float* b_in  = (const float*)d_in[16];
    const float* w_out = (const float*)d_in[17];
    const float* b_out = (const float*)d_in[18];

    float* out = (float*)d_out;
    // ws layout:
    //   [0, 16.78 MB):  mh fp32 [M][128]          (k1 -> k2)
    //   [16.78, 33.55): inputs bf16 [M][256]      (k3a -> k3b)
    // d_out doubles as h_ioT bf16 [B][256][128]   (k2 -> k3a), overwritten by k3b.
    float* mh     = (float*)d_ws;
    short* inputs = (short*)((char*)d_ws + (size_t)M_ * D_ * 4);
    short* hioT   = (short*)d_out;

    k1_gru_mfma<<<M_ / 32, 512, 0, stream>>>(xa, len, gwih, gwhh, gbih, gbhh, mh);
    k2_mfma    <<<B_,      512, 0, stream>>>(mi, mh, w_in, b_in, w_out, b_out, hioT);
    k3a_einsum <<<B_,      512, 0, stream>>>(A, hioT, biah, bioh, inputs);
    k3b_gate   <<<M_/128,  512, 0, stream>>>(inputs, hidden, wih, whh, bih, bhh, out);
}